// Round 1
// baseline (286.595 us; speedup 1.0000x reference)
//
#include <hip/hip_runtime.h>
#include <math.h>

#define BATCH 64
#define A_TOTAL 8649
#define PRE 1000
#define POST 256
#define NBINS 4096
#define NW 16            // 1000 bits -> 16 u64 words
#define NG (PRE / 4)     // 250 groups of 4 rows in the scan
#define PFD 8            // prefetch depth (groups)

// ---------------- K1: per-batch exact top-1000 + box decode ----------------
__global__ __launch_bounds__(256) void k_topk_decode(
    const float* __restrict__ deltas,   // [B][A][4]
    const float* __restrict__ probs,    // [B][A]
    const float* __restrict__ anchors,  // [A][4] yxyx
    float4* __restrict__ tboxes,        // [B][PRE]
    float* __restrict__ tscores)        // [B][PRE]
{
    #pragma clang fp contract(off)
    const int b = blockIdx.x;
    const int t = threadIdx.x;
    __shared__ unsigned int hist[NBINS];
    __shared__ unsigned long long cand[2048];
    __shared__ unsigned int gsum[256];
    __shared__ unsigned int s_cnt;
    __shared__ unsigned int s_thr;

    for (int i = t; i < NBINS; i += 256) hist[i] = 0u;
    if (t == 0) s_cnt = 0u;
    __syncthreads();

    const float* pr = probs + (size_t)b * A_TOTAL;
    for (int i = t; i < A_TOTAL; i += 256) {
        unsigned int bits = __float_as_uint(pr[i]);       // probs in [0,1): bit order == value order
        unsigned int bin = bits >> 18; if (bin > NBINS - 1) bin = NBINS - 1;
        atomicAdd(&hist[bin], 1u);
    }
    __syncthreads();

    // group sums (16 bins per group), then inclusive suffix scan over groups
    unsigned int gs = 0;
    #pragma unroll
    for (int q = 0; q < 16; ++q) gs += hist[t * 16 + q];
    gsum[t] = gs;
    __syncthreads();
    for (int off = 1; off < 256; off <<= 1) {
        unsigned int add = (t + off < 256) ? gsum[t + off] : 0u;
        __syncthreads();
        gsum[t] += add;
        __syncthreads();
    }
    // find threshold bin T = largest bin with count(bins >= T) >= PRE
    if (gsum[t] >= PRE && (t == 255 || gsum[t + 1] < PRE)) {
        unsigned int cum = (t == 255) ? 0u : gsum[t + 1];
        int bin = t * 16 + 15;
        while (bin > t * 16) {
            cum += hist[bin];
            if (cum >= PRE) break;
            --bin;
        }
        s_thr = (unsigned int)bin;
    }
    __syncthreads();

    // compact all candidates with bin >= T (count in [1000, ~1140])
    const unsigned int T = s_thr;
    for (int i = t; i < A_TOTAL; i += 256) {
        unsigned int bits = __float_as_uint(pr[i]);
        unsigned int bin = bits >> 18; if (bin > NBINS - 1) bin = NBINS - 1;
        if (bin >= T) {
            unsigned int p = atomicAdd(&s_cnt, 1u);
            if (p < 2048u)
                cand[p] = ((unsigned long long)bits << 32) |
                          (unsigned long long)(0xFFFFFFFFu - (unsigned int)i);
        }
    }
    __syncthreads();
    unsigned int n = s_cnt; if (n > 2048u) n = 2048u;
    for (int i = (int)n + t; i < 2048; i += 256) cand[i] = 0ull;  // pad sorts last
    __syncthreads();

    // bitonic sort, descending; key = (score_bits, ~idx) -> score desc, idx asc
    for (int k = 2; k <= 2048; k <<= 1) {
        for (int j = k >> 1; j > 0; j >>= 1) {
            for (int i = t; i < 2048; i += 256) {
                int ixj = i ^ j;
                if (ixj > i) {
                    unsigned long long x = cand[i], y = cand[ixj];
                    bool up = ((i & k) == 0);
                    if (up ? (x < y) : (x > y)) { cand[i] = y; cand[ixj] = x; }
                }
            }
            __syncthreads();
        }
    }

    // decode top-1000 boxes (mirror reference op order; exp via double = correctly-rounded f32)
    const float4* anc4 = (const float4*)anchors;
    const float4* dl4  = (const float4*)(deltas + (size_t)b * A_TOTAL * 4);
    for (int i = t; i < PRE; i += 256) {
        unsigned long long key = cand[i];
        unsigned int idx = 0xFFFFFFFFu - (unsigned int)(key & 0xFFFFFFFFull);
        float sc = __uint_as_float((unsigned int)(key >> 32));
        float4 a = anc4[idx];
        float4 d = dl4[idx];
        float ah  = a.z - a.x;
        float aw  = a.w - a.y;
        float acy = a.x + 0.5f * ah;
        float acx = a.y + 0.5f * aw;
        float ty = d.x * 0.1f, tx = d.y * 0.1f, th = d.z * 0.2f, tw = d.w * 0.2f;
        float h = (float)exp((double)th) * ah;
        float w = (float)exp((double)tw) * aw;
        float cy = ty * ah + acy;
        float cx = tx * aw + acx;
        float4 bx = make_float4(cy - 0.5f * h, cx - 0.5f * w, cy + 0.5f * h, cx + 0.5f * w);
        tboxes[(size_t)b * PRE + i] = bx;
        tscores[(size_t)b * PRE + i] = sc;
    }
}

// ---------------- K2: suppression bitmask build ----------------
__global__ __launch_bounds__(1024) void k_masks(
    const float4* __restrict__ tboxes,          // [B][PRE]
    unsigned long long* __restrict__ masks)     // [B][PRE][NW]
{
    #pragma clang fp contract(off)
    const int b = blockIdx.y;
    __shared__ float4 sb[PRE];
    for (int i = threadIdx.x; i < PRE; i += 1024) sb[i] = tboxes[(size_t)b * PRE + i];
    __syncthreads();
    const int wave = threadIdx.x >> 6;
    const int lane = threadIdx.x & 63;
    const int i = blockIdx.x * 16 + wave;
    if (i >= PRE) return;
    const float4 bi = sb[i];
    const float areai = (bi.z - bi.x) * (bi.w - bi.y);
    unsigned long long myword = 0ull;
    #pragma unroll
    for (int w = 0; w < NW; ++w) {
        const int j = (w << 6) + lane;
        bool sup = false;
        if (j < PRE && j > i) {
            const float4 bj = sb[j];
            float y1 = fmaxf(bi.x, bj.x);
            float x1 = fmaxf(bi.y, bj.y);
            float y2 = fminf(bi.z, bj.z);
            float x2 = fminf(bi.w, bj.w);
            float inter = fmaxf(y2 - y1, 0.0f) * fmaxf(x2 - x1, 0.0f);
            float areaj = (bj.z - bj.x) * (bj.w - bj.y);
            float uni = (areai + areaj) - inter;        // same assoc as reference
            float iou = inter / fmaxf(uni, 1e-8f);      // exact reference op sequence
            sup = iou > 0.8f;
        }
        unsigned long long m = __ballot(sup);
        if (lane == w) myword = m;
    }
    if (lane < NW) masks[((size_t)b * PRE + (size_t)i) * NW + lane] = myword;
}

// ---------------- K3: sequential greedy scan + output ----------------
__global__ __launch_bounds__(64) void k_nms_out(
    const float4* __restrict__ tboxes,
    const float* __restrict__ tscores,
    const unsigned long long* __restrict__ masks,
    float* __restrict__ out)   // [B*POST*4] boxes then [B*POST] scores
{
    #pragma clang fp contract(off)
    const int b = blockIdx.x;
    const int lane = threadIdx.x;
    const unsigned long long* Mb = masks + (size_t)b * PRE * NW;

    // lane l holds, for the current group of 4 rows, row (l>>4)'s word (l&15);
    // group g's 64 words are contiguous at Mb[g*64 .. g*64+63].
    unsigned long long pf[PFD];
    #pragma unroll
    for (int d = 0; d < PFD; ++d) pf[d] = Mb[d * 64 + lane];
    unsigned long long removed = 0ull;   // lane l maintains removed word (l&15) (replicated)
    for (int g = 0; g < NG; ++g) {
        unsigned long long cur = pf[g & (PFD - 1)];
        int gn = g + PFD;
        if (gn < NG) pf[g & (PFD - 1)] = Mb[gn * 64 + lane];
        #pragma unroll
        for (int di = 0; di < 4; ++di) {
            int i = (g << 2) + di;
            unsigned long long rw = __shfl(removed, i >> 6);   // uniform across lanes
            if (!((rw >> (i & 63)) & 1ull)) {
                unsigned long long m = __shfl(cur, (di << 4) + (lane & 15));
                removed |= m;
            }
        }
    }

    // order-preserving compaction of kept rows, first POST only
    const int w = lane & 15;
    unsigned long long keepw = ~removed;
    if (w == 15) keepw &= ((1ull << 40) - 1ull);   // rows 960..999 valid only
    int cnt = __popcll(keepw);
    int pre = 0, tot = 0;
    for (int q = 0; q < 16; ++q) {
        int c = __shfl(cnt, q);
        if (q < w) pre += c;
        tot += c;
    }
    __shared__ int sidx[POST];
    __shared__ int s_k;
    if (lane == 0) s_k = (tot < POST) ? tot : POST;
    if (lane < 16) {
        int rank = pre;
        unsigned long long x = keepw;
        while (x && rank < POST) {
            int p = __ffsll((unsigned long long)x) - 1;
            sidx[rank++] = (w << 6) + p;
            x &= (x - 1ull);
        }
    }
    __syncthreads();
    const int kc = s_k;
    const float4* bb = tboxes + (size_t)b * PRE;
    const float* ss = tscores + (size_t)b * PRE;
    float4* oB = (float4*)out + (size_t)b * POST;
    float* oS = out + (size_t)BATCH * POST * 4 + (size_t)b * POST;
    for (int t2 = lane; t2 < POST; t2 += 64) {
        float4 v = make_float4(0.f, 0.f, 0.f, 0.f);
        float sc = 0.f;
        if (t2 < kc) {
            int r = sidx[t2];
            float4 bx = bb[r];
            v.x = fminf(fmaxf(bx.x, 0.f), 1.f);
            v.y = fminf(fmaxf(bx.y, 0.f), 1.f);
            v.z = fminf(fmaxf(bx.z, 0.f), 1.f);
            v.w = fminf(fmaxf(bx.w, 0.f), 1.f);
            sc = ss[r];
        }
        oB[t2] = v;
        oS[t2] = sc;
    }
}

extern "C" void kernel_launch(void* const* d_in, const int* in_sizes, int n_in,
                              void* d_out, int out_size, void* d_ws, size_t ws_size,
                              hipStream_t stream) {
    const float* deltas  = (const float*)d_in[0];   // [64,8649,4] f32
    const float* probs   = (const float*)d_in[1];   // [64,8649]   f32
    const float* anchors = (const float*)d_in[3];   // [8649,4]    f32
    float* out = (float*)d_out;

    char* ws = (char*)d_ws;
    float4* tboxes = (float4*)ws;                                   // 1,024,000 B
    float* tscores = (float*)(ws + 1024000);                        //   256,000 B
    unsigned long long* masks = (unsigned long long*)(ws + 1280000);// 8,192,000 B

    k_topk_decode<<<dim3(BATCH), dim3(256), 0, stream>>>(deltas, probs, anchors, tboxes, tscores);
    k_masks<<<dim3((PRE + 15) / 16, BATCH), dim3(1024), 0, stream>>>(tboxes, masks);
    k_nms_out<<<dim3(BATCH), dim3(64), 0, stream>>>(tboxes, tscores, masks, out);
}

// Round 2
// 191.211 us; speedup vs baseline: 1.4988x; 1.4988x over previous
//
#include <hip/hip_runtime.h>
#include <math.h>

#define BATCH 64
#define A_TOTAL 8649
#define PRE 1000
#define POST 256
#define NBINS 4096
#define NW 16            // 1000 bits -> 16 u64 words

// ---------------- K1: per-batch exact top-1000 + box decode ----------------
__global__ __launch_bounds__(256) void k_topk_decode(
    const float* __restrict__ deltas,   // [B][A][4]
    const float* __restrict__ probs,    // [B][A]
    const float* __restrict__ anchors,  // [A][4] yxyx
    float4* __restrict__ tboxes,        // [B][PRE]
    float* __restrict__ tscores)        // [B][PRE]
{
    #pragma clang fp contract(off)
    const int b = blockIdx.x;
    const int t = threadIdx.x;
    __shared__ unsigned int hist[NBINS];
    __shared__ unsigned long long cand[2048];
    __shared__ unsigned int gsum[256];
    __shared__ unsigned int s_cnt;
    __shared__ unsigned int s_thr;

    for (int i = t; i < NBINS; i += 256) hist[i] = 0u;
    if (t == 0) s_cnt = 0u;
    __syncthreads();

    const float* pr = probs + (size_t)b * A_TOTAL;
    for (int i = t; i < A_TOTAL; i += 256) {
        unsigned int bits = __float_as_uint(pr[i]);       // probs in [0,1): bit order == value order
        unsigned int bin = bits >> 18; if (bin > NBINS - 1) bin = NBINS - 1;
        atomicAdd(&hist[bin], 1u);
    }
    __syncthreads();

    // group sums (16 bins per group), then inclusive suffix scan over groups
    unsigned int gs = 0;
    #pragma unroll
    for (int q = 0; q < 16; ++q) gs += hist[t * 16 + q];
    gsum[t] = gs;
    __syncthreads();
    for (int off = 1; off < 256; off <<= 1) {
        unsigned int add = (t + off < 256) ? gsum[t + off] : 0u;
        __syncthreads();
        gsum[t] += add;
        __syncthreads();
    }
    // find threshold bin T = largest bin with count(bins >= T) >= PRE
    if (gsum[t] >= PRE && (t == 255 || gsum[t + 1] < PRE)) {
        unsigned int cum = (t == 255) ? 0u : gsum[t + 1];
        int bin = t * 16 + 15;
        while (bin > t * 16) {
            cum += hist[bin];
            if (cum >= PRE) break;
            --bin;
        }
        s_thr = (unsigned int)bin;
    }
    __syncthreads();

    // compact all candidates with bin >= T (count in [1000, ~1140])
    const unsigned int T = s_thr;
    for (int i = t; i < A_TOTAL; i += 256) {
        unsigned int bits = __float_as_uint(pr[i]);
        unsigned int bin = bits >> 18; if (bin > NBINS - 1) bin = NBINS - 1;
        if (bin >= T) {
            unsigned int p = atomicAdd(&s_cnt, 1u);
            if (p < 2048u)
                cand[p] = ((unsigned long long)bits << 32) |
                          (unsigned long long)(0xFFFFFFFFu - (unsigned int)i);
        }
    }
    __syncthreads();
    unsigned int n = s_cnt; if (n > 2048u) n = 2048u;
    for (int i = (int)n + t; i < 2048; i += 256) cand[i] = 0ull;  // pad sorts last
    __syncthreads();

    // bitonic sort, descending; key = (score_bits, ~idx) -> score desc, idx asc
    for (int k = 2; k <= 2048; k <<= 1) {
        for (int j = k >> 1; j > 0; j >>= 1) {
            for (int i = t; i < 2048; i += 256) {
                int ixj = i ^ j;
                if (ixj > i) {
                    unsigned long long x = cand[i], y = cand[ixj];
                    bool up = ((i & k) == 0);
                    if (up ? (x < y) : (x > y)) { cand[i] = y; cand[ixj] = x; }
                }
            }
            __syncthreads();
        }
    }

    // decode top-1000 boxes (mirror reference op order; exp via double = correctly-rounded f32)
    const float4* anc4 = (const float4*)anchors;
    const float4* dl4  = (const float4*)(deltas + (size_t)b * A_TOTAL * 4);
    for (int i = t; i < PRE; i += 256) {
        unsigned long long key = cand[i];
        unsigned int idx = 0xFFFFFFFFu - (unsigned int)(key & 0xFFFFFFFFull);
        float sc = __uint_as_float((unsigned int)(key >> 32));
        float4 a = anc4[idx];
        float4 d = dl4[idx];
        float ah  = a.z - a.x;
        float aw  = a.w - a.y;
        float acy = a.x + 0.5f * ah;
        float acx = a.y + 0.5f * aw;
        float ty = d.x * 0.1f, tx = d.y * 0.1f, th = d.z * 0.2f, tw = d.w * 0.2f;
        float h = (float)exp((double)th) * ah;
        float w = (float)exp((double)tw) * aw;
        float cy = ty * ah + acy;
        float cx = tx * aw + acx;
        float4 bx = make_float4(cy - 0.5f * h, cx - 0.5f * w, cy + 0.5f * h, cx + 0.5f * w);
        tboxes[(size_t)b * PRE + i] = bx;
        tscores[(size_t)b * PRE + i] = sc;
    }
}

// ---------------- K2: suppression bitmask build ----------------
// Decision equivalence: RN(inter/u) > 0.8f  <=>  inter >= (0.8f + 2^-25) * u
// (0.8f has odd mantissa so the halfway point rounds up; the double product of a
// 25-bit x 24-bit significand is exact). Bit-identical to the f32 divide+compare.
__global__ __launch_bounds__(1024) void k_masks(
    const float4* __restrict__ tboxes,          // [B][PRE]
    unsigned long long* __restrict__ masks)     // [B][PRE][NW]
{
    #pragma clang fp contract(off)
    const int b = blockIdx.y;
    __shared__ float4 sb[PRE];
    for (int i = threadIdx.x; i < PRE; i += 1024) sb[i] = tboxes[(size_t)b * PRE + i];
    __syncthreads();
    const int wave = threadIdx.x >> 6;
    const int lane = threadIdx.x & 63;
    const int row0 = blockIdx.x * 250;
    const double C = (double)0.8f + 0x1p-25;
    for (int i = row0 + wave; i < row0 + 250; i += 16) {
        const float4 bi = sb[i];
        const float areai = (bi.z - bi.x) * (bi.w - bi.y);
        const int w0 = i >> 6;                 // words below the diagonal are all-zero
        unsigned long long myword = 0ull;
        for (int w = w0; w < NW; ++w) {
            const int j = (w << 6) + lane;
            bool sup = false;
            if (j < PRE && j > i) {
                const float4 bj = sb[j];
                float y1 = fmaxf(bi.x, bj.x);
                float x1 = fmaxf(bi.y, bj.y);
                float y2 = fminf(bi.z, bj.z);
                float x2 = fminf(bi.w, bj.w);
                float inter = fmaxf(y2 - y1, 0.0f) * fmaxf(x2 - x1, 0.0f);
                float areaj = (bj.z - bj.x) * (bj.w - bj.y);
                float uni = (areai + areaj) - inter;        // same assoc as reference
                float u = fmaxf(uni, 1e-8f);
                sup = ((double)inter >= C * (double)u);     // == (inter/u > 0.8f) exactly
            }
            unsigned long long m = __ballot(sup);
            if (lane == w) myword = m;
        }
        if (lane < NW) masks[((size_t)b * PRE + (size_t)i) * NW + lane] = myword;
    }
}

// ---------------- K3: ffs-driven greedy scan + output ----------------
// First alive row is always kept -> iterate only kept rows (<=256 with early stop).
// removed mask distributed: lane l accumulates word (l&15) as one of 4 group
// partials; merged by 4 readlanes when a word's scan starts.
__global__ __launch_bounds__(64) void k_nms_out(
    const float4* __restrict__ tboxes,
    const float* __restrict__ tscores,
    const unsigned long long* __restrict__ masks,
    float* __restrict__ out)   // [B*POST*4] boxes then [B*POST] scores
{
    #pragma clang fp contract(off)
    const int b = blockIdx.x;
    const int lane = threadIdx.x;
    const unsigned long long* Mb = masks + (size_t)b * PRE * NW;
    const int wword = lane & 15;
    const int wgrp  = lane >> 4;
    __shared__ int sidx[POST];

    // prefetch diagonal words: lane l -> row W*64+l's word W (16 independent loads)
    unsigned int dlo[NW], dhi[NW];
    #pragma unroll
    for (int W = 0; W < NW; ++W) {
        const int base = W << 6;
        const int nvalid = (PRE - base < 64) ? (PRE - base) : 64;
        const int drow = base + ((lane < nvalid) ? lane : 0);
        unsigned long long dv = Mb[(size_t)drow * NW + W];
        if (lane >= nvalid) dv = 0ull;
        dlo[W] = (unsigned int)dv;
        dhi[W] = (unsigned int)(dv >> 32);
    }

    unsigned long long rm = 0ull;   // distributed removed word (l&15), group partial
    int kc = 0;
    bool done = false;
    #pragma unroll
    for (int W = 0; W < NW; ++W) {
        const int base = W << 6;
        // merge the 4 group partials of removed word W -> uniform
        unsigned int rlo = (unsigned int)__builtin_amdgcn_readlane((int)(unsigned int)rm, W)
                         | (unsigned int)__builtin_amdgcn_readlane((int)(unsigned int)rm, W + 16)
                         | (unsigned int)__builtin_amdgcn_readlane((int)(unsigned int)rm, W + 32)
                         | (unsigned int)__builtin_amdgcn_readlane((int)(unsigned int)rm, W + 48);
        unsigned int rhi = (unsigned int)__builtin_amdgcn_readlane((int)(unsigned int)(rm >> 32), W)
                         | (unsigned int)__builtin_amdgcn_readlane((int)(unsigned int)(rm >> 32), W + 16)
                         | (unsigned int)__builtin_amdgcn_readlane((int)(unsigned int)(rm >> 32), W + 32)
                         | (unsigned int)__builtin_amdgcn_readlane((int)(unsigned int)(rm >> 32), W + 48);
        unsigned long long rmW = ((unsigned long long)rhi << 32) | (unsigned long long)rlo;
        unsigned long long valid = (PRE - base >= 64) ? ~0ull : ((1ull << (PRE - base)) - 1ull);
        unsigned long long alive = ~rmW & valid;
        unsigned long long keptw = 0ull;
        while (alive) {
            int i = __builtin_amdgcn_readfirstlane(__ffsll(alive) - 1);
            keptw |= (1ull << i);
            if (lane == 0) sidx[kc] = base + i;
            ++kc;
            if (kc == POST) { done = true; break; }
            unsigned int dl = (unsigned int)__builtin_amdgcn_readlane((int)dlo[W], i);
            unsigned int dh = (unsigned int)__builtin_amdgcn_readlane((int)dhi[W], i);
            unsigned long long d = ((unsigned long long)dh << 32) | (unsigned long long)dl;
            alive &= ~(d | (1ull << i));
        }
        if (done) break;
        // flush kept rows' masks into distributed rm; 4 rows/round, 2 rounds in flight
        unsigned long long kw = keptw;
        while (kw) {
            unsigned long long tA = kw;
            if (wgrp > 0) tA &= tA - 1ull;
            if (wgrp > 1) tA &= tA - 1ull;
            if (wgrp > 2) tA &= tA - 1ull;
            const bool vA = (tA != 0ull);
            const int rA = base + (vA ? (__ffsll(tA) - 1) : 0);
            unsigned long long kw2 = kw;
            kw2 &= kw2 - 1ull; kw2 &= kw2 - 1ull; kw2 &= kw2 - 1ull; kw2 &= kw2 - 1ull;
            unsigned long long tB = kw2;
            if (wgrp > 0) tB &= tB - 1ull;
            if (wgrp > 1) tB &= tB - 1ull;
            if (wgrp > 2) tB &= tB - 1ull;
            const bool vB = (tB != 0ull);
            const int rB = base + (vB ? (__ffsll(tB) - 1) : 0);
            kw = kw2;
            kw &= kw - 1ull; kw &= kw - 1ull; kw &= kw - 1ull; kw &= kw - 1ull;
            unsigned long long mA = Mb[(size_t)rA * NW + wword];
            unsigned long long mB = Mb[(size_t)rB * NW + wword];
            if (!vA) mA = 0ull;
            if (!vB) mB = 0ull;
            rm |= mA | mB;
        }
    }
    __syncthreads();

    const float4* bb = tboxes + (size_t)b * PRE;
    const float* ss = tscores + (size_t)b * PRE;
    float4* oB = (float4*)out + (size_t)b * POST;
    float* oS = out + (size_t)BATCH * POST * 4 + (size_t)b * POST;
    for (int t2 = lane; t2 < POST; t2 += 64) {
        float4 v = make_float4(0.f, 0.f, 0.f, 0.f);
        float sc = 0.f;
        if (t2 < kc) {
            int r = sidx[t2];
            float4 bx = bb[r];
            v.x = fminf(fmaxf(bx.x, 0.f), 1.f);
            v.y = fminf(fmaxf(bx.y, 0.f), 1.f);
            v.z = fminf(fmaxf(bx.z, 0.f), 1.f);
            v.w = fminf(fmaxf(bx.w, 0.f), 1.f);
            sc = ss[r];
        }
        oB[t2] = v;
        oS[t2] = sc;
    }
}

extern "C" void kernel_launch(void* const* d_in, const int* in_sizes, int n_in,
                              void* d_out, int out_size, void* d_ws, size_t ws_size,
                              hipStream_t stream) {
    const float* deltas  = (const float*)d_in[0];   // [64,8649,4] f32
    const float* probs   = (const float*)d_in[1];   // [64,8649]   f32
    const float* anchors = (const float*)d_in[3];   // [8649,4]    f32
    float* out = (float*)d_out;

    char* ws = (char*)d_ws;
    float4* tboxes = (float4*)ws;                                   // 1,024,000 B
    float* tscores = (float*)(ws + 1024000);                        //   256,000 B
    unsigned long long* masks = (unsigned long long*)(ws + 1280000);// 8,192,000 B

    k_topk_decode<<<dim3(BATCH), dim3(256), 0, stream>>>(deltas, probs, anchors, tboxes, tscores);
    k_masks<<<dim3(4, BATCH), dim3(1024), 0, stream>>>(tboxes, masks);
    k_nms_out<<<dim3(BATCH), dim3(64), 0, stream>>>(tboxes, tscores, masks, out);
}

// Round 3
// 152.780 us; speedup vs baseline: 1.8759x; 1.2515x over previous
//
#include <hip/hip_runtime.h>
#include <math.h>

#define BATCH 64
#define A_TOTAL 8649
#define PRE 1000
#define POST 256
#define NBINS 4096
#define NW 16            // 1000 bits -> 16 u64 words

// ---------------- K1: per-batch exact top-1000 + box decode ----------------
// Sort-free: histogram -> threshold bin -> compact candidates (~1140) ->
// rank-by-counting (keys unique) -> decode + scatter to tboxes[b][rank].
__global__ __launch_bounds__(1024) void k_topk_decode(
    const float* __restrict__ deltas,   // [B][A][4]
    const float* __restrict__ probs,    // [B][A]
    const float* __restrict__ anchors,  // [A][4] yxyx
    float4* __restrict__ tboxes,        // [B][PRE]
    float* __restrict__ tscores)        // [B][PRE]
{
    #pragma clang fp contract(off)
    const int b = blockIdx.x;
    const int t = threadIdx.x;
    __shared__ unsigned int hist[NBINS];
    __shared__ unsigned long long cand[2048];
    __shared__ unsigned int gsum[256];
    __shared__ unsigned int s_cnt;
    __shared__ unsigned int s_thr;

    for (int i = t; i < NBINS; i += 1024) hist[i] = 0u;
    if (t == 0) s_cnt = 0u;
    __syncthreads();

    const float* pr = probs + (size_t)b * A_TOTAL;
    for (int i = t; i < A_TOTAL; i += 1024) {
        unsigned int bits = __float_as_uint(pr[i]);       // probs in [0,1): bit order == value order
        unsigned int bin = bits >> 18; if (bin > NBINS - 1) bin = NBINS - 1;
        atomicAdd(&hist[bin], 1u);
    }
    __syncthreads();

    // group sums (16 bins per group), then inclusive suffix scan over groups
    if (t < 256) {
        unsigned int gs = 0;
        #pragma unroll
        for (int q = 0; q < 16; ++q) gs += hist[t * 16 + q];
        gsum[t] = gs;
    }
    __syncthreads();
    for (int off = 1; off < 256; off <<= 1) {
        unsigned int add = (t < 256 && t + off < 256) ? gsum[t + off] : 0u;
        __syncthreads();
        if (t < 256) gsum[t] += add;
        __syncthreads();
    }
    // find threshold bin T = largest bin with count(bins >= T) >= PRE
    if (t < 256 && gsum[t] >= PRE && (t == 255 || gsum[t + 1] < PRE)) {
        unsigned int cum = (t == 255) ? 0u : gsum[t + 1];
        int bin = t * 16 + 15;
        while (bin > t * 16) {
            cum += hist[bin];
            if (cum >= PRE) break;
            --bin;
        }
        s_thr = (unsigned int)bin;
    }
    __syncthreads();

    // compact all candidates with bin >= T (count in [1000, ~1140])
    const unsigned int T = s_thr;
    for (int i = t; i < A_TOTAL; i += 1024) {
        unsigned int bits = __float_as_uint(pr[i]);
        unsigned int bin = bits >> 18; if (bin > NBINS - 1) bin = NBINS - 1;
        if (bin >= T) {
            unsigned int p = atomicAdd(&s_cnt, 1u);
            if (p < 2048u)
                cand[p] = ((unsigned long long)bits << 32) |
                          (unsigned long long)(0xFFFFFFFFu - (unsigned int)i);
        }
    }
    __syncthreads();
    const int n = (s_cnt > 2048u) ? 2048 : (int)s_cnt;

    // rank-by-counting: key order = (score desc, idx asc); keys unique.
    // Broadcast LDS reads -> no bank conflicts, no barriers.
    unsigned long long k0 = (t < n) ? cand[t] : 0ull;
    unsigned long long k1 = (t + 1024 < n) ? cand[t + 1024] : 0ull;
    unsigned int r0 = 0, r1 = 0;
    #pragma unroll 4
    for (int j = 0; j < n; ++j) {
        unsigned long long kj = cand[j];
        r0 += (kj > k0);
        r1 += (kj > k1);
    }

    // decode + scatter (mirror reference op order; exp via double = correctly-rounded f32)
    const float4* anc4 = (const float4*)anchors;
    const float4* dl4  = (const float4*)(deltas + (size_t)b * A_TOTAL * 4);
    #pragma unroll
    for (int c = 0; c < 2; ++c) {
        const bool valid = (c == 0) ? (t < n && r0 < PRE) : (t + 1024 < n && r1 < PRE);
        if (!valid) continue;
        unsigned long long key = (c == 0) ? k0 : k1;
        unsigned int rank = (c == 0) ? r0 : r1;
        unsigned int idx = 0xFFFFFFFFu - (unsigned int)(key & 0xFFFFFFFFull);
        float sc = __uint_as_float((unsigned int)(key >> 32));
        float4 a = anc4[idx];
        float4 d = dl4[idx];
        float ah  = a.z - a.x;
        float aw  = a.w - a.y;
        float acy = a.x + 0.5f * ah;
        float acx = a.y + 0.5f * aw;
        float ty = d.x * 0.1f, tx = d.y * 0.1f, th = d.z * 0.2f, tw = d.w * 0.2f;
        float h = (float)exp((double)th) * ah;
        float w = (float)exp((double)tw) * aw;
        float cy = ty * ah + acy;
        float cx = tx * aw + acx;
        float4 bx = make_float4(cy - 0.5f * h, cx - 0.5f * w, cy + 0.5f * h, cx + 0.5f * w);
        tboxes[(size_t)b * PRE + rank] = bx;
        tscores[(size_t)b * PRE + rank] = sc;
    }
}

// ---------------- K2: suppression bitmask build ----------------
// Decision equivalence: RN(inter/u) > 0.8f  <=>  inter >= (0.8f + 2^-25) * u
// (0.8f has odd mantissa so the halfway point rounds up; the double product of a
// 25-bit x 24-bit significand is exact). Bit-identical to the f32 divide+compare.
__global__ __launch_bounds__(1024) void k_masks(
    const float4* __restrict__ tboxes,          // [B][PRE]
    unsigned long long* __restrict__ masks)     // [B][PRE][NW]
{
    #pragma clang fp contract(off)
    const int b = blockIdx.y;
    __shared__ float4 sb[PRE];
    for (int i = threadIdx.x; i < PRE; i += 1024) sb[i] = tboxes[(size_t)b * PRE + i];
    __syncthreads();
    const int wave = threadIdx.x >> 6;
    const int lane = threadIdx.x & 63;
    const int row0 = blockIdx.x * 250;
    const double C = (double)0.8f + 0x1p-25;
    for (int i = row0 + wave; i < row0 + 250; i += 16) {
        const float4 bi = sb[i];
        const float areai = (bi.z - bi.x) * (bi.w - bi.y);
        const int w0 = i >> 6;                 // words below the diagonal are all-zero
        unsigned long long myword = 0ull;
        for (int w = w0; w < NW; ++w) {
            const int j = (w << 6) + lane;
            bool sup = false;
            if (j < PRE && j > i) {
                const float4 bj = sb[j];
                float y1 = fmaxf(bi.x, bj.x);
                float x1 = fmaxf(bi.y, bj.y);
                float y2 = fminf(bi.z, bj.z);
                float x2 = fminf(bi.w, bj.w);
                float inter = fmaxf(y2 - y1, 0.0f) * fmaxf(x2 - x1, 0.0f);
                float areaj = (bj.z - bj.x) * (bj.w - bj.y);
                float uni = (areai + areaj) - inter;        // same assoc as reference
                float u = fmaxf(uni, 1e-8f);
                sup = ((double)inter >= C * (double)u);     // == (inter/u > 0.8f) exactly
            }
            unsigned long long m = __ballot(sup);
            if (lane == w) myword = m;
        }
        if (lane < NW) masks[((size_t)b * PRE + (size_t)i) * NW + lane] = myword;
    }
}

// ---------------- K3: ffs-driven greedy scan + output ----------------
// First alive row is always kept -> iterate only kept rows (<=256 with early stop).
// removed mask distributed: lane l accumulates word (l&15) as one of 4 group
// partials; merged by 4 readlanes when a word's scan starts.
__global__ __launch_bounds__(64) void k_nms_out(
    const float4* __restrict__ tboxes,
    const float* __restrict__ tscores,
    const unsigned long long* __restrict__ masks,
    float* __restrict__ out)   // [B*POST*4] boxes then [B*POST] scores
{
    #pragma clang fp contract(off)
    const int b = blockIdx.x;
    const int lane = threadIdx.x;
    const unsigned long long* Mb = masks + (size_t)b * PRE * NW;
    const int wword = lane & 15;
    const int wgrp  = lane >> 4;
    __shared__ int sidx[POST];

    // prefetch diagonal words: lane l -> row W*64+l's word W (16 independent loads)
    unsigned int dlo[NW], dhi[NW];
    #pragma unroll
    for (int W = 0; W < NW; ++W) {
        const int base = W << 6;
        const int nvalid = (PRE - base < 64) ? (PRE - base) : 64;
        const int drow = base + ((lane < nvalid) ? lane : 0);
        unsigned long long dv = Mb[(size_t)drow * NW + W];
        if (lane >= nvalid) dv = 0ull;
        dlo[W] = (unsigned int)dv;
        dhi[W] = (unsigned int)(dv >> 32);
    }

    unsigned long long rm = 0ull;   // distributed removed word (l&15), group partial
    int kc = 0;
    bool done = false;
    #pragma unroll
    for (int W = 0; W < NW; ++W) {
        const int base = W << 6;
        // merge the 4 group partials of removed word W -> uniform
        unsigned int rlo = (unsigned int)__builtin_amdgcn_readlane((int)(unsigned int)rm, W)
                         | (unsigned int)__builtin_amdgcn_readlane((int)(unsigned int)rm, W + 16)
                         | (unsigned int)__builtin_amdgcn_readlane((int)(unsigned int)rm, W + 32)
                         | (unsigned int)__builtin_amdgcn_readlane((int)(unsigned int)rm, W + 48);
        unsigned int rhi = (unsigned int)__builtin_amdgcn_readlane((int)(unsigned int)(rm >> 32), W)
                         | (unsigned int)__builtin_amdgcn_readlane((int)(unsigned int)(rm >> 32), W + 16)
                         | (unsigned int)__builtin_amdgcn_readlane((int)(unsigned int)(rm >> 32), W + 32)
                         | (unsigned int)__builtin_amdgcn_readlane((int)(unsigned int)(rm >> 32), W + 48);
        unsigned long long rmW = ((unsigned long long)rhi << 32) | (unsigned long long)rlo;
        unsigned long long valid = (PRE - base >= 64) ? ~0ull : ((1ull << (PRE - base)) - 1ull);
        unsigned long long alive = ~rmW & valid;
        unsigned long long keptw = 0ull;
        while (alive) {
            int i = __builtin_amdgcn_readfirstlane(__ffsll(alive) - 1);
            keptw |= (1ull << i);
            if (lane == 0) sidx[kc] = base + i;
            ++kc;
            if (kc == POST) { done = true; break; }
            unsigned int dl = (unsigned int)__builtin_amdgcn_readlane((int)dlo[W], i);
            unsigned int dh = (unsigned int)__builtin_amdgcn_readlane((int)dhi[W], i);
            unsigned long long d = ((unsigned long long)dh << 32) | (unsigned long long)dl;
            alive &= ~(d | (1ull << i));
        }
        if (done) break;
        // flush kept rows' masks into distributed rm; 4 rows/round, 2 rounds in flight
        unsigned long long kw = keptw;
        while (kw) {
            unsigned long long tA = kw;
            if (wgrp > 0) tA &= tA - 1ull;
            if (wgrp > 1) tA &= tA - 1ull;
            if (wgrp > 2) tA &= tA - 1ull;
            const bool vA = (tA != 0ull);
            const int rA = base + (vA ? (__ffsll(tA) - 1) : 0);
            unsigned long long kw2 = kw;
            kw2 &= kw2 - 1ull; kw2 &= kw2 - 1ull; kw2 &= kw2 - 1ull; kw2 &= kw2 - 1ull;
            unsigned long long tB = kw2;
            if (wgrp > 0) tB &= tB - 1ull;
            if (wgrp > 1) tB &= tB - 1ull;
            if (wgrp > 2) tB &= tB - 1ull;
            const bool vB = (tB != 0ull);
            const int rB = base + (vB ? (__ffsll(tB) - 1) : 0);
            kw = kw2;
            kw &= kw - 1ull; kw &= kw - 1ull; kw &= kw - 1ull; kw &= kw - 1ull;
            unsigned long long mA = Mb[(size_t)rA * NW + wword];
            unsigned long long mB = Mb[(size_t)rB * NW + wword];
            if (!vA) mA = 0ull;
            if (!vB) mB = 0ull;
            rm |= mA | mB;
        }
    }
    __syncthreads();

    const float4* bb = tboxes + (size_t)b * PRE;
    const float* ss = tscores + (size_t)b * PRE;
    float4* oB = (float4*)out + (size_t)b * POST;
    float* oS = out + (size_t)BATCH * POST * 4 + (size_t)b * POST;
    for (int t2 = lane; t2 < POST; t2 += 64) {
        float4 v = make_float4(0.f, 0.f, 0.f, 0.f);
        float sc = 0.f;
        if (t2 < kc) {
            int r = sidx[t2];
            float4 bx = bb[r];
            v.x = fminf(fmaxf(bx.x, 0.f), 1.f);
            v.y = fminf(fmaxf(bx.y, 0.f), 1.f);
            v.z = fminf(fmaxf(bx.z, 0.f), 1.f);
            v.w = fminf(fmaxf(bx.w, 0.f), 1.f);
            sc = ss[r];
        }
        oB[t2] = v;
        oS[t2] = sc;
    }
}

extern "C" void kernel_launch(void* const* d_in, const int* in_sizes, int n_in,
                              void* d_out, int out_size, void* d_ws, size_t ws_size,
                              hipStream_t stream) {
    const float* deltas  = (const float*)d_in[0];   // [64,8649,4] f32
    const float* probs   = (const float*)d_in[1];   // [64,8649]   f32
    const float* anchors = (const float*)d_in[3];   // [8649,4]    f32
    float* out = (float*)d_out;

    char* ws = (char*)d_ws;
    float4* tboxes = (float4*)ws;                                   // 1,024,000 B
    float* tscores = (float*)(ws + 1024000);                        //   256,000 B
    unsigned long long* masks = (unsigned long long*)(ws + 1280000);// 8,192,000 B

    k_topk_decode<<<dim3(BATCH), dim3(1024), 0, stream>>>(deltas, probs, anchors, tboxes, tscores);
    k_masks<<<dim3(4, BATCH), dim3(1024), 0, stream>>>(tboxes, masks);
    k_nms_out<<<dim3(BATCH), dim3(64), 0, stream>>>(tboxes, tscores, masks, out);
}

// Round 4
// 99.688 us; speedup vs baseline: 2.8749x; 1.5326x over previous
//
#include <hip/hip_runtime.h>
#include <math.h>

#define BATCH 64
#define A_TOTAL 8649
#define PRE 1000
#define POST 256
#define NBINS 4096
#define NW 16            // 1000 bits -> 16 u64 words

// ---------------- K1: per-batch exact top-1000 + box decode ----------------
// Histogram -> per-bin exact suffix counts (exc) -> threshold bin -> bin-grouped
// compaction -> rank = exc[bin] + within-bin count (segments avg ~2) -> decode
// + scatter to tboxes[b][rank]. Keys unique -> deterministic.
__global__ __launch_bounds__(1024) void k_topk_decode(
    const float* __restrict__ deltas,   // [B][A][4]
    const float* __restrict__ probs,    // [B][A]
    const float* __restrict__ anchors,  // [A][4] yxyx
    float4* __restrict__ tboxes,        // [B][PRE]
    float* __restrict__ tscores)        // [B][PRE]
{
    #pragma clang fp contract(off)
    const int b = blockIdx.x;
    const int t = threadIdx.x;
    __shared__ unsigned int hist[NBINS];   // reused as per-bin scatter counters
    __shared__ unsigned int exc[NBINS];    // # anchors with bin' > bin
    __shared__ unsigned long long cand[2048];
    __shared__ unsigned int gsum[256];
    __shared__ unsigned int s_thr;
    __shared__ unsigned int s_n;

    for (int i = t; i < NBINS; i += 1024) hist[i] = 0u;
    __syncthreads();

    const float* pr = probs + (size_t)b * A_TOTAL;
    for (int i = t; i < A_TOTAL; i += 1024) {
        unsigned int bits = __float_as_uint(pr[i]);   // probs in [0,1): bit order == value order
        atomicAdd(&hist[bits >> 18], 1u);
    }
    __syncthreads();

    // 16-bin group sums, inclusive suffix scan over 256 groups
    if (t < 256) {
        unsigned int gs = 0;
        #pragma unroll
        for (int q = 0; q < 16; ++q) gs += hist[t * 16 + q];
        gsum[t] = gs;
    }
    __syncthreads();
    for (int off = 1; off < 256; off <<= 1) {
        unsigned int add = (t < 256 && t + off < 256) ? gsum[t + off] : 0u;
        __syncthreads();
        if (t < 256) gsum[t] += add;
        __syncthreads();
    }
    // per-bin exclusive suffix counts
    if (t < 256) {
        unsigned int run = (t == 255) ? 0u : gsum[t + 1];
        for (int q = 15; q >= 0; --q) {
            int bin = t * 16 + q;
            exc[bin] = run;
            run += hist[bin];
        }
    }
    __syncthreads();
    // threshold bin T = max bin with (exc+hist) >= PRE; n = candidates at/above T
    for (int bin = t; bin < NBINS; bin += 1024) {
        unsigned int ge = exc[bin] + hist[bin];
        unsigned int ge1 = (bin == NBINS - 1) ? 0u : (exc[bin + 1] + hist[bin + 1]);
        if (ge >= PRE && ge1 < PRE) { s_thr = (unsigned int)bin; s_n = ge; }
    }
    __syncthreads();
    const unsigned int T = s_thr;
    const int n = (s_n > 2048u) ? 2048 : (int)s_n;
    // reuse hist as per-bin scatter counters
    for (int i = t; i < NBINS; i += 1024) hist[i] = 0u;
    __syncthreads();

    // bin-grouped compaction: bin b's candidates land in [exc[b], exc[b]+cnt[b])
    for (int i = t; i < A_TOTAL; i += 1024) {
        unsigned int bits = __float_as_uint(pr[i]);
        unsigned int bin = bits >> 18;
        if (bin >= T) {
            unsigned int p = exc[bin] + atomicAdd(&hist[bin], 1u);
            if (p < 2048u)
                cand[p] = ((unsigned long long)bits << 32) |
                          (unsigned long long)(0xFFFFFFFFu - (unsigned int)i);
        }
    }
    __syncthreads();

    // rank within segment + decode + scatter
    const float4* anc4 = (const float4*)anchors;
    const float4* dl4  = (const float4*)(deltas + (size_t)b * A_TOTAL * 4);
    for (int p = t; p < n; p += 1024) {
        unsigned long long key = cand[p];
        unsigned int bin = (unsigned int)(key >> 50);       // score_bits >> 18
        int segs = (int)exc[bin];
        int sege = (bin > 0) ? (int)exc[bin - 1] : n;       // exc[b-1] == exc[b]+hist_orig[b]
        if (sege > 2048) sege = 2048;
        unsigned int rank = (unsigned int)segs;
        for (int q = segs; q < sege; ++q) rank += (cand[q] > key);
        if (rank >= PRE) continue;
        unsigned int idx = 0xFFFFFFFFu - (unsigned int)(key & 0xFFFFFFFFull);
        float sc = __uint_as_float((unsigned int)(key >> 32));
        float4 a = anc4[idx];
        float4 d = dl4[idx];
        float ah  = a.z - a.x;
        float aw  = a.w - a.y;
        float acy = a.x + 0.5f * ah;
        float acx = a.y + 0.5f * aw;
        float ty = d.x * 0.1f, tx = d.y * 0.1f, th = d.z * 0.2f, tw = d.w * 0.2f;
        float h = (float)exp((double)th) * ah;
        float w = (float)exp((double)tw) * aw;
        float cy = ty * ah + acy;
        float cx = tx * aw + acx;
        float4 bx = make_float4(cy - 0.5f * h, cx - 0.5f * w, cy + 0.5f * h, cx + 0.5f * w);
        tboxes[(size_t)b * PRE + rank] = bx;
        tscores[(size_t)b * PRE + rank] = sc;
    }
}

// ---------------- K2: suppression bitmask build (transposed 64x64 tiles) ----------------
// lane = row, iterate j: broadcast LDS reads, per-lane register mask word.
// Only upper-triangle tiles (W >= I) are computed/stored; K3 masks sub-diagonal
// words (structurally zero) on its flush reads.
// Decision equivalence: RN(inter/u) > 0.8f  <=>  inter >= (0.8f + 2^-25) * u
// (0.8f has odd mantissa -> halfway rounds up; 25x24-bit double product exact).
__global__ __launch_bounds__(256) void k_masks(
    const float4* __restrict__ tboxes,          // [B][PRE]
    unsigned long long* __restrict__ masks)     // [B][PRE][NW]
{
    #pragma clang fp contract(off)
    const int b = blockIdx.y;
    __shared__ float4 sbox[PRE];
    __shared__ float sarea[PRE];
    for (int i = threadIdx.x; i < PRE; i += 256) {
        float4 v = tboxes[(size_t)b * PRE + i];
        sbox[i] = v;
        sarea[i] = (v.z - v.x) * (v.w - v.y);
    }
    __syncthreads();

    // tile id -> (I, W), upper triangle row-major: I has (16-I) tiles
    int f = blockIdx.x * 4 + (threadIdx.x >> 6);
    int I = 0;
    while (f >= 16 - I) { f -= 16 - I; ++I; }
    const int W = I + f;
    const int lane = threadIdx.x & 63;
    const int row = (I << 6) + lane;
    const int rr = (row < PRE) ? row : 0;
    const float4 bi = sbox[rr];
    const float areai = sarea[rr];
    const int Jbase = W << 6;
    const int jmax = (PRE - Jbase < 64) ? (PRE - Jbase) : 64;
    const double C = (double)0.8f + 0x1p-25;
    const bool diag = (I == W);
    unsigned int mlo = 0u, mhi = 0u;
    for (int jj = 0; jj < jmax; ++jj) {
        const int j = Jbase + jj;
        const float4 bj = sbox[j];
        const float aj = sarea[j];
        float y1 = fmaxf(bi.x, bj.x);
        float x1 = fmaxf(bi.y, bj.y);
        float y2 = fminf(bi.z, bj.z);
        float x2 = fminf(bi.w, bj.w);
        float inter = fmaxf(y2 - y1, 0.0f) * fmaxf(x2 - x1, 0.0f);
        float uni = (areai + aj) - inter;              // same assoc as reference
        float u = fmaxf(uni, 1e-8f);
        bool sup = ((double)inter >= C * (double)u);   // == (inter/u > 0.8f) exactly
        if (diag) sup = sup && (lane < jj);            // strict j > i on diagonal
        unsigned int s = sup ? (1u << (jj & 31)) : 0u;
        if (jj < 32) mlo |= s; else mhi |= s;          // uniform branch
    }
    if (row < PRE)
        masks[((size_t)b * PRE + (size_t)row) * NW + W] =
            ((unsigned long long)mhi << 32) | (unsigned long long)mlo;
}

// ---------------- K3: ffs-driven greedy scan + output ----------------
// First alive row is always kept -> iterate only kept rows (<=256 with early stop).
__global__ __launch_bounds__(64) void k_nms_out(
    const float4* __restrict__ tboxes,
    const float* __restrict__ tscores,
    const unsigned long long* __restrict__ masks,
    float* __restrict__ out)   // [B*POST*4] boxes then [B*POST] scores
{
    #pragma clang fp contract(off)
    const int b = blockIdx.x;
    const int lane = threadIdx.x;
    const unsigned long long* Mb = masks + (size_t)b * PRE * NW;
    const int wword = lane & 15;
    const int wgrp  = lane >> 4;
    __shared__ int sidx[POST];

    // prefetch diagonal words: lane l -> row W*64+l's word W (16 independent loads)
    unsigned int dlo[NW], dhi[NW];
    #pragma unroll
    for (int W = 0; W < NW; ++W) {
        const int base = W << 6;
        const int nvalid = (PRE - base < 64) ? (PRE - base) : 64;
        const int drow = base + ((lane < nvalid) ? lane : 0);
        unsigned long long dv = Mb[(size_t)drow * NW + W];
        if (lane >= nvalid) dv = 0ull;
        dlo[W] = (unsigned int)dv;
        dhi[W] = (unsigned int)(dv >> 32);
    }

    unsigned long long rm = 0ull;   // distributed removed word (l&15), group partial
    int kc = 0;
    bool done = false;
    #pragma unroll
    for (int W = 0; W < NW; ++W) {
        const int base = W << 6;
        // merge the 4 group partials of removed word W -> uniform
        unsigned int rlo = (unsigned int)__builtin_amdgcn_readlane((int)(unsigned int)rm, W)
                         | (unsigned int)__builtin_amdgcn_readlane((int)(unsigned int)rm, W + 16)
                         | (unsigned int)__builtin_amdgcn_readlane((int)(unsigned int)rm, W + 32)
                         | (unsigned int)__builtin_amdgcn_readlane((int)(unsigned int)rm, W + 48);
        unsigned int rhi = (unsigned int)__builtin_amdgcn_readlane((int)(unsigned int)(rm >> 32), W)
                         | (unsigned int)__builtin_amdgcn_readlane((int)(unsigned int)(rm >> 32), W + 16)
                         | (unsigned int)__builtin_amdgcn_readlane((int)(unsigned int)(rm >> 32), W + 32)
                         | (unsigned int)__builtin_amdgcn_readlane((int)(unsigned int)(rm >> 32), W + 48);
        unsigned long long rmW = ((unsigned long long)rhi << 32) | (unsigned long long)rlo;
        unsigned long long valid = (PRE - base >= 64) ? ~0ull : ((1ull << (PRE - base)) - 1ull);
        unsigned long long alive = ~rmW & valid;
        unsigned long long keptw = 0ull;
        while (alive) {
            int i = __builtin_amdgcn_readfirstlane(__ffsll(alive) - 1);
            keptw |= (1ull << i);
            if (lane == 0) sidx[kc] = base + i;
            ++kc;
            if (kc == POST) { done = true; break; }
            unsigned int dl = (unsigned int)__builtin_amdgcn_readlane((int)dlo[W], i);
            unsigned int dh = (unsigned int)__builtin_amdgcn_readlane((int)dhi[W], i);
            unsigned long long d = ((unsigned long long)dh << 32) | (unsigned long long)dl;
            alive &= ~(d | (1ull << i));
        }
        if (done) break;
        // flush kept rows' masks into distributed rm; 8 rows per round (A+B)
        unsigned long long kw = keptw;
        while (kw) {
            unsigned long long tA = kw;
            if (wgrp > 0) tA &= tA - 1ull;
            if (wgrp > 1) tA &= tA - 1ull;
            if (wgrp > 2) tA &= tA - 1ull;
            const bool vA = (tA != 0ull);
            const int rA = base + (vA ? (__ffsll(tA) - 1) : 0);
            unsigned long long kw2 = kw;
            kw2 &= kw2 - 1ull; kw2 &= kw2 - 1ull; kw2 &= kw2 - 1ull; kw2 &= kw2 - 1ull;
            unsigned long long tB = kw2;
            if (wgrp > 0) tB &= tB - 1ull;
            if (wgrp > 1) tB &= tB - 1ull;
            if (wgrp > 2) tB &= tB - 1ull;
            const bool vB = (tB != 0ull);
            const int rB = base + (vB ? (__ffsll(tB) - 1) : 0);
            kw = kw2;
            kw &= kw - 1ull; kw &= kw - 1ull; kw &= kw - 1ull; kw &= kw - 1ull;
            unsigned long long mA = Mb[(size_t)rA * NW + wword];
            unsigned long long mB = Mb[(size_t)rB * NW + wword];
            // sub-diagonal words are structurally zero (not written by K2)
            if (!vA || wword < (rA >> 6)) mA = 0ull;
            if (!vB || wword < (rB >> 6)) mB = 0ull;
            rm |= mA | mB;
        }
    }
    __syncthreads();

    const float4* bb = tboxes + (size_t)b * PRE;
    const float* ss = tscores + (size_t)b * PRE;
    float4* oB = (float4*)out + (size_t)b * POST;
    float* oS = out + (size_t)BATCH * POST * 4 + (size_t)b * POST;
    for (int t2 = lane; t2 < POST; t2 += 64) {
        float4 v = make_float4(0.f, 0.f, 0.f, 0.f);
        float sc = 0.f;
        if (t2 < kc) {
            int r = sidx[t2];
            float4 bx = bb[r];
            v.x = fminf(fmaxf(bx.x, 0.f), 1.f);
            v.y = fminf(fmaxf(bx.y, 0.f), 1.f);
            v.z = fminf(fmaxf(bx.z, 0.f), 1.f);
            v.w = fminf(fmaxf(bx.w, 0.f), 1.f);
            sc = ss[r];
        }
        oB[t2] = v;
        oS[t2] = sc;
    }
}

extern "C" void kernel_launch(void* const* d_in, const int* in_sizes, int n_in,
                              void* d_out, int out_size, void* d_ws, size_t ws_size,
                              hipStream_t stream) {
    const float* deltas  = (const float*)d_in[0];   // [64,8649,4] f32
    const float* probs   = (const float*)d_in[1];   // [64,8649]   f32
    const float* anchors = (const float*)d_in[3];   // [8649,4]    f32
    float* out = (float*)d_out;

    char* ws = (char*)d_ws;
    float4* tboxes = (float4*)ws;                                   // 1,024,000 B
    float* tscores = (float*)(ws + 1024000);                        //   256,000 B
    unsigned long long* masks = (unsigned long long*)(ws + 1280000);// 8,192,000 B

    k_topk_decode<<<dim3(BATCH), dim3(1024), 0, stream>>>(deltas, probs, anchors, tboxes, tscores);
    k_masks<<<dim3(34, BATCH), dim3(256), 0, stream>>>(tboxes, masks);
    k_nms_out<<<dim3(BATCH), dim3(64), 0, stream>>>(tboxes, tscores, masks, out);
}

// Round 5
// 97.875 us; speedup vs baseline: 2.9282x; 1.0185x over previous
//
#include <hip/hip_runtime.h>
#include <math.h>

#define BATCH 64
#define A_TOTAL 8649
#define PRE 1000
#define POST 256
#define NBINS 4096
#define NW 16            // 1000 bits -> 16 u64 words
#define TRI_WORDS 7680   // 64 * sum_{I=0..14}(15-I) = 64*120 (upper-tri minus diag)

// ---------------- K1: per-batch exact top-1000 + box decode ----------------
// Histogram -> per-bin exact suffix counts (exc) -> threshold bin -> bin-grouped
// compaction -> rank = exc[bin] + within-bin count (segments small) -> decode
// + scatter to tboxes/tscores/tareas[b][rank]. Keys unique -> deterministic.
__global__ __launch_bounds__(1024) void k_topk_decode(
    const float* __restrict__ deltas,   // [B][A][4]
    const float* __restrict__ probs,    // [B][A]
    const float* __restrict__ anchors,  // [A][4] yxyx
    float4* __restrict__ tboxes,        // [B][PRE]
    float* __restrict__ tscores,        // [B][PRE]
    float* __restrict__ tareas)         // [B][PRE]
{
    #pragma clang fp contract(off)
    const int b = blockIdx.x;
    const int t = threadIdx.x;
    __shared__ unsigned int hist[NBINS];   // reused as per-bin scatter counters
    __shared__ unsigned int exc[NBINS];    // # anchors with bin' > bin
    __shared__ unsigned long long cand[2048];
    __shared__ unsigned int gsum[256];
    __shared__ unsigned int s_thr;
    __shared__ unsigned int s_n;

    for (int i = t; i < NBINS; i += 1024) hist[i] = 0u;
    __syncthreads();

    const float* pr = probs + (size_t)b * A_TOTAL;
    for (int i = t; i < A_TOTAL; i += 1024) {
        unsigned int bits = __float_as_uint(pr[i]);   // probs in [0,1): bit order == value order
        atomicAdd(&hist[bits >> 18], 1u);
    }
    __syncthreads();

    // 16-bin group partial sums
    if (t < 256) {
        unsigned int gs = 0;
        #pragma unroll
        for (int q = 0; q < 16; ++q) gs += hist[t * 16 + q];
        gsum[t] = gs;
    }
    __syncthreads();
    // single-wave inclusive suffix scan over 256 groups (4 groups per lane)
    if (t < 64) {
        const int l = t;
        unsigned int a  = gsum[4 * l];
        unsigned int b2 = gsum[4 * l + 1];
        unsigned int c  = gsum[4 * l + 2];
        unsigned int d  = gsum[4 * l + 3];
        unsigned int quad = a + b2 + c + d;
        unsigned int q = quad;
        #pragma unroll
        for (int off = 1; off < 64; off <<= 1) {
            unsigned int v = __shfl_down(q, off);
            q += (l + off < 64) ? v : 0u;
        }
        // q = inclusive suffix of quads starting at this lane
        gsum[4 * l]     = q;                 // groups 4l..255
        gsum[4 * l + 1] = q - a;
        gsum[4 * l + 2] = q - a - b2;
        gsum[4 * l + 3] = q - a - b2 - c;
    }
    __syncthreads();
    // per-bin exclusive suffix counts
    if (t < 256) {
        unsigned int run = (t == 255) ? 0u : gsum[t + 1];
        for (int q = 15; q >= 0; --q) {
            int bin = t * 16 + q;
            exc[bin] = run;
            run += hist[bin];
        }
    }
    __syncthreads();
    // threshold bin T = max bin with (exc+hist) >= PRE; n = candidates at/above T
    for (int bin = t; bin < NBINS; bin += 1024) {
        unsigned int ge = exc[bin] + hist[bin];
        unsigned int ge1 = (bin == NBINS - 1) ? 0u : (exc[bin + 1] + hist[bin + 1]);
        if (ge >= PRE && ge1 < PRE) { s_thr = (unsigned int)bin; s_n = ge; }
    }
    __syncthreads();
    const unsigned int T = s_thr;
    const int n = (s_n > 2048u) ? 2048 : (int)s_n;
    // reuse hist as per-bin scatter counters
    for (int i = t; i < NBINS; i += 1024) hist[i] = 0u;
    __syncthreads();

    // bin-grouped compaction: bin k's candidates land in [exc[k], exc[k]+cnt[k])
    for (int i = t; i < A_TOTAL; i += 1024) {
        unsigned int bits = __float_as_uint(pr[i]);
        unsigned int bin = bits >> 18;
        if (bin >= T) {
            unsigned int p = exc[bin] + atomicAdd(&hist[bin], 1u);
            if (p < 2048u)
                cand[p] = ((unsigned long long)bits << 32) |
                          (unsigned long long)(0xFFFFFFFFu - (unsigned int)i);
        }
    }
    __syncthreads();

    // rank within segment + decode + scatter
    const float4* anc4 = (const float4*)anchors;
    const float4* dl4  = (const float4*)(deltas + (size_t)b * A_TOTAL * 4);
    for (int p = t; p < n; p += 1024) {
        unsigned long long key = cand[p];
        unsigned int bin = (unsigned int)(key >> 50);       // score_bits >> 18
        int segs = (int)exc[bin];
        int sege = (bin > 0) ? (int)exc[bin - 1] : n;       // exc[b-1] == exc[b]+hist_orig[b]
        if (sege > 2048) sege = 2048;
        unsigned int rank = (unsigned int)segs;
        for (int q = segs; q < sege; ++q) rank += (cand[q] > key);
        if (rank >= PRE) continue;
        unsigned int idx = 0xFFFFFFFFu - (unsigned int)(key & 0xFFFFFFFFull);
        float sc = __uint_as_float((unsigned int)(key >> 32));
        float4 a = anc4[idx];
        float4 d = dl4[idx];
        float ah  = a.z - a.x;
        float aw  = a.w - a.y;
        float acy = a.x + 0.5f * ah;
        float acx = a.y + 0.5f * aw;
        float ty = d.x * 0.1f, tx = d.y * 0.1f, th = d.z * 0.2f, tw = d.w * 0.2f;
        float h = (float)exp((double)th) * ah;
        float w = (float)exp((double)tw) * aw;
        float cy = ty * ah + acy;
        float cx = tx * aw + acx;
        float4 bx = make_float4(cy - 0.5f * h, cx - 0.5f * w, cy + 0.5f * h, cx + 0.5f * w);
        tboxes[(size_t)b * PRE + rank] = bx;
        tscores[(size_t)b * PRE + rank] = sc;
        tareas[(size_t)b * PRE + rank] = (bx.z - bx.x) * (bx.w - bx.y);
    }
}

// ---------------- K2: suppression bitmask build (64x64 tiles, no LDS) ----------------
// lane = row; j-side operands are wave-uniform -> scalar/broadcast loads straight
// from global (L1/K$-resident: 20KB per batch). Only upper-triangle tiles stored.
// Decision equivalence: RN(inter/u) > 0.8f  <=>  inter >= (0.8f + 2^-25) * u
// (0.8f has odd mantissa -> halfway rounds up; 25x24-bit double product exact).
__global__ __launch_bounds__(256) void k_masks(
    const float4* __restrict__ tboxes,          // [B][PRE]
    const float* __restrict__ tareas,           // [B][PRE]
    unsigned long long* __restrict__ masks)     // [B][PRE][NW]
{
    #pragma clang fp contract(off)
    const int b = blockIdx.y;
    // tile id -> (I, W), upper triangle row-major: I has (16-I) tiles
    int f = blockIdx.x * 4 + (threadIdx.x >> 6);
    f = __builtin_amdgcn_readfirstlane(f);      // pin wave-uniform -> SGPR
    int I = 0;
    while (f >= 16 - I) { f -= 16 - I; ++I; }
    const int W = I + f;
    const int lane = threadIdx.x & 63;
    const int row = (I << 6) + lane;
    const int rr = (row < PRE) ? row : 0;
    const float4 bi = tboxes[(size_t)b * PRE + rr];
    const float areai = tareas[(size_t)b * PRE + rr];
    const float4* __restrict__ bjp = tboxes + (size_t)b * PRE + (W << 6);
    const float*  __restrict__ ajp = tareas + (size_t)b * PRE + (W << 6);
    const int jmax = (PRE - (W << 6) < 64) ? (PRE - (W << 6)) : 64;
    const double C = (double)0.8f + 0x1p-25;
    const bool diag = (I == W);
    unsigned int mlo = 0u, mhi = 0u;

#define IOU_SUP(jj, sup) do { \
        const float4 bj = bjp[jj]; \
        const float aj = ajp[jj]; \
        float y1 = fmaxf(bi.x, bj.x); \
        float x1 = fmaxf(bi.y, bj.y); \
        float y2 = fminf(bi.z, bj.z); \
        float x2 = fminf(bi.w, bj.w); \
        float inter = fmaxf(y2 - y1, 0.0f) * fmaxf(x2 - x1, 0.0f); \
        float uni = (areai + aj) - inter;            /* same assoc as reference */ \
        float u = fmaxf(uni, 1e-8f); \
        sup = ((double)inter >= C * (double)u);      /* == (inter/u > 0.8f) exactly */ \
        if (diag) sup = sup && (lane < (jj)); \
    } while (0)

    if (jmax == 64) {
        #pragma unroll 4
        for (int jj = 0; jj < 32; ++jj) {
            bool sup; IOU_SUP(jj, sup);
            mlo |= sup ? (1u << jj) : 0u;
        }
        #pragma unroll 4
        for (int jj = 32; jj < 64; ++jj) {
            bool sup; IOU_SUP(jj, sup);
            mhi |= sup ? (1u << (jj - 32)) : 0u;
        }
    } else {
        for (int jj = 0; jj < jmax; ++jj) {
            bool sup; IOU_SUP(jj, sup);
            unsigned int s = sup ? (1u << (jj & 31)) : 0u;
            if (jj < 32) mlo |= s; else mhi |= s;
        }
    }
#undef IOU_SUP
    if (row < PRE)
        masks[((size_t)b * PRE + (size_t)row) * NW + W] =
            ((unsigned long long)mhi << 32) | (unsigned long long)mlo;
}

// ---------------- K3: ffs-driven greedy scan + output ----------------
// Stage the batch's upper-tri-minus-diag mask words (7680 u64 = 60KB) in LDS with
// 4 waves; wave 0 scans: first alive row is always kept -> iterate only kept rows
// (<=256 with early stop). Flush reads come from LDS; diagonal words from regs.
__global__ __launch_bounds__(256) void k_nms_out(
    const float4* __restrict__ tboxes,
    const float* __restrict__ tscores,
    const unsigned long long* __restrict__ masks,
    float* __restrict__ out)   // [B*POST*4] boxes then [B*POST] scores
{
    #pragma clang fp contract(off)
    const int b = blockIdx.x;
    const int tid = threadIdx.x;
    const unsigned long long* Mb = masks + (size_t)b * PRE * NW;
    __shared__ unsigned long long Ml[TRI_WORDS];
    __shared__ int sidx[POST];
    __shared__ int s_kc;

    // wave0: prefetch diagonal words: lane l -> row W*64+l's word W
    unsigned int dlo[NW], dhi[NW];
    if (tid < 64) {
        const int lane = tid;
        #pragma unroll
        for (int W = 0; W < NW; ++W) {
            const int base = W << 6;
            const int nvalid = (PRE - base < 64) ? (PRE - base) : 64;
            const int drow = base + ((lane < nvalid) ? lane : 0);
            unsigned long long dv = Mb[(size_t)drow * NW + W];
            if (lane >= nvalid) dv = 0ull;
            dlo[W] = (unsigned int)dv;
            dhi[W] = (unsigned int)(dv >> 32);
        }
    }

    // all threads: stage upper-tri-minus-diag words into LDS (compact layout)
    #pragma unroll
    for (int I = 0; I < 15; ++I) {
        const int cnt = 15 - I;
        const int base = 64 * (15 * I - (I * (I - 1)) / 2);
        const int total = 64 * cnt;
        for (int idx = tid; idx < total; idx += 256) {
            const int r = (I << 6) + idx / cnt;
            const int w = I + 1 + (idx % cnt);
            Ml[base + idx] = Mb[(size_t)r * NW + w];
        }
    }
    __syncthreads();

    if (tid < 64) {
        const int lane = tid;
        const int wword = lane & 15;
        const int wgrp  = lane >> 4;
        unsigned long long rm = 0ull;   // distributed removed word (l&15), group partial
        int kc = 0;
        bool done = false;
        #pragma unroll
        for (int W = 0; W < NW; ++W) {
            const int base = W << 6;
            // merge the 4 group partials of removed word W -> uniform
            unsigned int rlo = (unsigned int)__builtin_amdgcn_readlane((int)(unsigned int)rm, W)
                             | (unsigned int)__builtin_amdgcn_readlane((int)(unsigned int)rm, W + 16)
                             | (unsigned int)__builtin_amdgcn_readlane((int)(unsigned int)rm, W + 32)
                             | (unsigned int)__builtin_amdgcn_readlane((int)(unsigned int)rm, W + 48);
            unsigned int rhi = (unsigned int)__builtin_amdgcn_readlane((int)(unsigned int)(rm >> 32), W)
                             | (unsigned int)__builtin_amdgcn_readlane((int)(unsigned int)(rm >> 32), W + 16)
                             | (unsigned int)__builtin_amdgcn_readlane((int)(unsigned int)(rm >> 32), W + 32)
                             | (unsigned int)__builtin_amdgcn_readlane((int)(unsigned int)(rm >> 32), W + 48);
            unsigned long long rmW = ((unsigned long long)rhi << 32) | (unsigned long long)rlo;
            unsigned long long valid = (PRE - base >= 64) ? ~0ull : ((1ull << (PRE - base)) - 1ull);
            unsigned long long alive = ~rmW & valid;
            unsigned long long keptw = 0ull;
            while (alive) {
                int i = __builtin_amdgcn_readfirstlane(__ffsll(alive) - 1);
                keptw |= (1ull << i);
                if (lane == 0) sidx[kc] = base + i;
                ++kc;
                if (kc == POST) { done = true; break; }
                unsigned int dl = (unsigned int)__builtin_amdgcn_readlane((int)dlo[W], i);
                unsigned int dh = (unsigned int)__builtin_amdgcn_readlane((int)dhi[W], i);
                unsigned long long d = ((unsigned long long)dh << 32) | (unsigned long long)dl;
                alive &= ~(d | (1ull << i));
            }
            if (done) break;
            // flush kept rows' masks into distributed rm; 8 rows per round (A+B)
            const int cntW = 15 - W;
            const int baseW = 64 * (15 * W - (W * (W - 1)) / 2);
            unsigned long long kw = keptw;
            while (kw) {
                unsigned long long tA = kw;
                if (wgrp > 0) tA &= tA - 1ull;
                if (wgrp > 1) tA &= tA - 1ull;
                if (wgrp > 2) tA &= tA - 1ull;
                const bool vA = (tA != 0ull);
                const int iA = vA ? (__ffsll(tA) - 1) : 0;
                unsigned long long kw2 = kw;
                kw2 &= kw2 - 1ull; kw2 &= kw2 - 1ull; kw2 &= kw2 - 1ull; kw2 &= kw2 - 1ull;
                unsigned long long tB = kw2;
                if (wgrp > 0) tB &= tB - 1ull;
                if (wgrp > 1) tB &= tB - 1ull;
                if (wgrp > 2) tB &= tB - 1ull;
                const bool vB = (tB != 0ull);
                const int iB = vB ? (__ffsll(tB) - 1) : 0;
                kw = kw2;
                kw &= kw - 1ull; kw &= kw - 1ull; kw &= kw - 1ull; kw &= kw - 1ull;
                // lane's word source for row i{A,B}: wword>W -> LDS; ==W -> diag regs; <W -> 0
                unsigned long long lA = 0ull, lB = 0ull;
                if (wword > W) {
                    lA = Ml[baseW + iA * cntW + (wword - W - 1)];
                    lB = Ml[baseW + iB * cntW + (wword - W - 1)];
                }
                unsigned long long gA =
                    ((unsigned long long)(unsigned int)__builtin_amdgcn_readlane((int)dhi[W], iA) << 32)
                  |  (unsigned long long)(unsigned int)__builtin_amdgcn_readlane((int)dlo[W], iA);
                unsigned long long gB =
                    ((unsigned long long)(unsigned int)__builtin_amdgcn_readlane((int)dhi[W], iB) << 32)
                  |  (unsigned long long)(unsigned int)__builtin_amdgcn_readlane((int)dlo[W], iB);
                unsigned long long mA = (wword > W) ? lA : ((wword == W) ? gA : 0ull);
                unsigned long long mB = (wword > W) ? lB : ((wword == W) ? gB : 0ull);
                if (!vA) mA = 0ull;
                if (!vB) mB = 0ull;
                rm |= mA | mB;
            }
        }
        if (tid == 0) s_kc = kc;
    }
    __syncthreads();

    const int kc = s_kc;
    const float4* bb = tboxes + (size_t)b * PRE;
    const float* ss = tscores + (size_t)b * PRE;
    float4* oB = (float4*)out + (size_t)b * POST;
    float* oS = out + (size_t)BATCH * POST * 4 + (size_t)b * POST;
    for (int t2 = tid; t2 < POST; t2 += 256) {
        float4 v = make_float4(0.f, 0.f, 0.f, 0.f);
        float sc = 0.f;
        if (t2 < kc) {
            int r = sidx[t2];
            float4 bx = bb[r];
            v.x = fminf(fmaxf(bx.x, 0.f), 1.f);
            v.y = fminf(fmaxf(bx.y, 0.f), 1.f);
            v.z = fminf(fmaxf(bx.z, 0.f), 1.f);
            v.w = fminf(fmaxf(bx.w, 0.f), 1.f);
            sc = ss[r];
        }
        oB[t2] = v;
        oS[t2] = sc;
    }
}

extern "C" void kernel_launch(void* const* d_in, const int* in_sizes, int n_in,
                              void* d_out, int out_size, void* d_ws, size_t ws_size,
                              hipStream_t stream) {
    const float* deltas  = (const float*)d_in[0];   // [64,8649,4] f32
    const float* probs   = (const float*)d_in[1];   // [64,8649]   f32
    const float* anchors = (const float*)d_in[3];   // [8649,4]    f32
    float* out = (float*)d_out;

    char* ws = (char*)d_ws;
    float4* tboxes = (float4*)ws;                                    // 1,024,000 B
    float* tscores = (float*)(ws + 1024000);                         //   256,000 B
    unsigned long long* masks = (unsigned long long*)(ws + 1280000); // 8,192,000 B
    float* tareas = (float*)(ws + 9472000);                          //   256,000 B

    k_topk_decode<<<dim3(BATCH), dim3(1024), 0, stream>>>(deltas, probs, anchors,
                                                          tboxes, tscores, tareas);
    k_masks<<<dim3(34, BATCH), dim3(256), 0, stream>>>(tboxes, tareas, masks);
    k_nms_out<<<dim3(BATCH), dim3(256), 0, stream>>>(tboxes, tscores, masks, out);
}

// Round 6
// 89.223 us; speedup vs baseline: 3.2121x; 1.0970x over previous
//
#include <hip/hip_runtime.h>
#include <math.h>

#define BATCH 64
#define A_TOTAL 8649
#define PRE 1000
#define POST 256
#define NBINS 4096
#define NW 16              // 1000 bits -> 16 u64 words
#define TRIG 120           // upper-tri-minus-diag column groups: sum_{I=0..14}(15-I)
#define TRIP 65            // padded group stride (bank-conflict-free flush reads)
#define TRI_WORDS (TRIG * TRIP)   // 7800 u64 per batch

// ---------------- K1: per-batch exact top-1000 + box decode ----------------
// Histogram -> per-bin exact suffix counts (exc) -> threshold bin -> bin-grouped
// compaction -> rank = exc[bin] + within-bin count (segments small) -> decode
// + scatter to tboxes/tscores/tareas[b][rank]. Keys unique -> deterministic.
__global__ __launch_bounds__(1024) void k_topk_decode(
    const float* __restrict__ deltas,   // [B][A][4]
    const float* __restrict__ probs,    // [B][A]
    const float* __restrict__ anchors,  // [A][4] yxyx
    float4* __restrict__ tboxes,        // [B][PRE]
    float* __restrict__ tscores,        // [B][PRE]
    float* __restrict__ tareas)         // [B][PRE]
{
    #pragma clang fp contract(off)
    const int b = blockIdx.x;
    const int t = threadIdx.x;
    __shared__ unsigned int hist[NBINS];   // reused as per-bin scatter counters
    __shared__ unsigned int exc[NBINS];    // # anchors with bin' > bin
    __shared__ unsigned int sbits[A_TOTAL];
    __shared__ unsigned long long cand[2048];
    __shared__ unsigned int gsum[256];
    __shared__ unsigned int s_thr;
    __shared__ unsigned int s_n;

    for (int i = t; i < NBINS; i += 1024) hist[i] = 0u;
    __syncthreads();

    const float* pr = probs + (size_t)b * A_TOTAL;
    for (int i = t; i < A_TOTAL; i += 1024) {
        unsigned int bits = __float_as_uint(pr[i]);   // probs in [0,1): bit order == value order
        sbits[i] = bits;
        atomicAdd(&hist[bits >> 18], 1u);
    }
    __syncthreads();

    // 16-bin group partial sums
    if (t < 256) {
        unsigned int gs = 0;
        #pragma unroll
        for (int q = 0; q < 16; ++q) gs += hist[t * 16 + q];
        gsum[t] = gs;
    }
    __syncthreads();
    // single-wave inclusive suffix scan over 256 groups (4 groups per lane)
    if (t < 64) {
        const int l = t;
        unsigned int a  = gsum[4 * l];
        unsigned int b2 = gsum[4 * l + 1];
        unsigned int c  = gsum[4 * l + 2];
        unsigned int d  = gsum[4 * l + 3];
        unsigned int quad = a + b2 + c + d;
        unsigned int q = quad;
        #pragma unroll
        for (int off = 1; off < 64; off <<= 1) {
            unsigned int v = __shfl_down(q, off);
            q += (l + off < 64) ? v : 0u;
        }
        gsum[4 * l]     = q;
        gsum[4 * l + 1] = q - a;
        gsum[4 * l + 2] = q - a - b2;
        gsum[4 * l + 3] = q - a - b2 - c;
    }
    __syncthreads();
    // per-bin exclusive suffix counts
    if (t < 256) {
        unsigned int run = (t == 255) ? 0u : gsum[t + 1];
        for (int q = 15; q >= 0; --q) {
            int bin = t * 16 + q;
            exc[bin] = run;
            run += hist[bin];
        }
    }
    __syncthreads();
    // threshold bin T = max bin with (exc+hist) >= PRE; n = candidates at/above T
    for (int bin = t; bin < NBINS; bin += 1024) {
        unsigned int ge = exc[bin] + hist[bin];
        unsigned int ge1 = (bin == NBINS - 1) ? 0u : (exc[bin + 1] + hist[bin + 1]);
        if (ge >= PRE && ge1 < PRE) { s_thr = (unsigned int)bin; s_n = ge; }
    }
    __syncthreads();
    const unsigned int T = s_thr;
    const int n = (s_n > 2048u) ? 2048 : (int)s_n;
    // reuse hist as per-bin scatter counters
    for (int i = t; i < NBINS; i += 1024) hist[i] = 0u;
    __syncthreads();

    // bin-grouped compaction: bin k's candidates land in [exc[k], exc[k]+cnt[k])
    for (int i = t; i < A_TOTAL; i += 1024) {
        unsigned int bits = sbits[i];
        unsigned int bin = bits >> 18;
        if (bin >= T) {
            unsigned int p = exc[bin] + atomicAdd(&hist[bin], 1u);
            if (p < 2048u)
                cand[p] = ((unsigned long long)bits << 32) |
                          (unsigned long long)(0xFFFFFFFFu - (unsigned int)i);
        }
    }
    __syncthreads();

    // rank within segment + decode + scatter
    const float4* anc4 = (const float4*)anchors;
    const float4* dl4  = (const float4*)(deltas + (size_t)b * A_TOTAL * 4);
    for (int p = t; p < n; p += 1024) {
        unsigned long long key = cand[p];
        unsigned int bin = (unsigned int)(key >> 50);       // score_bits >> 18
        int segs = (int)exc[bin];
        int sege = (bin > 0) ? (int)exc[bin - 1] : n;       // exc[b-1] == exc[b]+hist_orig[b]
        if (sege > 2048) sege = 2048;
        unsigned int rank = (unsigned int)segs;
        for (int q = segs; q < sege; ++q) rank += (cand[q] > key);
        if (rank >= PRE) continue;
        unsigned int idx = 0xFFFFFFFFu - (unsigned int)(key & 0xFFFFFFFFull);
        float sc = __uint_as_float((unsigned int)(key >> 32));
        float4 a = anc4[idx];
        float4 d = dl4[idx];
        float ah  = a.z - a.x;
        float aw  = a.w - a.y;
        float acy = a.x + 0.5f * ah;
        float acx = a.y + 0.5f * aw;
        float ty = d.x * 0.1f, tx = d.y * 0.1f, th = d.z * 0.2f, tw = d.w * 0.2f;
        float h = (float)exp((double)th) * ah;
        float w = (float)exp((double)tw) * aw;
        float cy = ty * ah + acy;
        float cx = tx * aw + acx;
        float4 bx = make_float4(cy - 0.5f * h, cx - 0.5f * w, cy + 0.5f * h, cx + 0.5f * w);
        tboxes[(size_t)b * PRE + rank] = bx;
        tscores[(size_t)b * PRE + rank] = sc;
        tareas[(size_t)b * PRE + rank] = (bx.z - bx.x) * (bx.w - bx.y);
    }
}

// ---------------- K2: suppression bitmask build (64x64 tiles, no LDS) ----------------
// lane = row; j-side operands are wave-uniform -> broadcast loads from global.
// Off-diag tile (I,W) stores to compact tri layout mtri[b][(CG(I)+(W-I-1))*65+lane];
// diag tile W stores mdiag[b][W*64+lane]. Both coalesced.
// Decision equivalence: RN(inter/u) > 0.8f  <=>  inter >= (0.8f + 2^-25) * u
// (0.8f has odd mantissa -> halfway rounds up; 25x24-bit double product exact).
__global__ __launch_bounds__(256) void k_masks(
    const float4* __restrict__ tboxes,          // [B][PRE]
    const float* __restrict__ tareas,           // [B][PRE]
    unsigned long long* __restrict__ mtri,      // [B][TRI_WORDS]
    unsigned long long* __restrict__ mdiag)     // [B][NW*64]
{
    #pragma clang fp contract(off)
    const int b = blockIdx.y;
    // tile id -> (I, W), upper triangle row-major: I has (16-I) tiles
    int f = blockIdx.x * 4 + (threadIdx.x >> 6);
    f = __builtin_amdgcn_readfirstlane(f);      // pin wave-uniform -> SGPR
    int I = 0;
    while (f >= 16 - I) { f -= 16 - I; ++I; }
    const int W = I + f;
    const int lane = threadIdx.x & 63;
    const int row = (I << 6) + lane;
    const int rr = (row < PRE) ? row : 0;
    const float4 bi = tboxes[(size_t)b * PRE + rr];
    const float areai = tareas[(size_t)b * PRE + rr];
    const float4* __restrict__ bjp = tboxes + (size_t)b * PRE + (W << 6);
    const float*  __restrict__ ajp = tareas + (size_t)b * PRE + (W << 6);
    const int jmax = (PRE - (W << 6) < 64) ? (PRE - (W << 6)) : 64;
    const double C = (double)0.8f + 0x1p-25;
    const bool diag = (I == W);
    unsigned int mlo = 0u, mhi = 0u;

#define IOU_SUP(jj, sup) do { \
        const float4 bj = bjp[jj]; \
        const float aj = ajp[jj]; \
        float y1 = fmaxf(bi.x, bj.x); \
        float x1 = fmaxf(bi.y, bj.y); \
        float y2 = fminf(bi.z, bj.z); \
        float x2 = fminf(bi.w, bj.w); \
        float inter = fmaxf(y2 - y1, 0.0f) * fmaxf(x2 - x1, 0.0f); \
        float uni = (areai + aj) - inter;            /* same assoc as reference */ \
        float u = fmaxf(uni, 1e-8f); \
        sup = ((double)inter >= C * (double)u);      /* == (inter/u > 0.8f) exactly */ \
        if (diag) sup = sup && (lane < (jj)); \
    } while (0)

    if (jmax == 64) {
        #pragma unroll 4
        for (int jj = 0; jj < 32; ++jj) {
            bool sup; IOU_SUP(jj, sup);
            mlo |= sup ? (1u << jj) : 0u;
        }
        #pragma unroll 4
        for (int jj = 32; jj < 64; ++jj) {
            bool sup; IOU_SUP(jj, sup);
            mhi |= sup ? (1u << (jj - 32)) : 0u;
        }
    } else {
        for (int jj = 0; jj < jmax; ++jj) {
            bool sup; IOU_SUP(jj, sup);
            unsigned int s = sup ? (1u << (jj & 31)) : 0u;
            if (jj < 32) mlo |= s; else mhi |= s;
        }
    }
#undef IOU_SUP
    const unsigned long long mword =
        ((unsigned long long)mhi << 32) | (unsigned long long)mlo;
    if (row < PRE) {
        if (diag) {
            mdiag[((size_t)b << 10) + (W << 6) + lane] = mword;
        } else {
            const int cg = 15 * I - (I * (I - 1)) / 2 + (W - I - 1);
            mtri[(size_t)b * TRI_WORDS + (size_t)cg * TRIP + lane] = mword;
        }
    }
}

// ---------------- K3: ffs-driven greedy scan + output ----------------
// Stage the compact tri mask block (62.4KB) into LDS with a linear float4 copy;
// diagonal words -> wave0 registers (coalesced 512B loads). Wave0 scans: first
// alive row is always kept -> iterate only kept rows (<=256 with early stop).
__global__ __launch_bounds__(512) void k_nms_out(
    const float4* __restrict__ tboxes,
    const float* __restrict__ tscores,
    const unsigned long long* __restrict__ mtri,
    const unsigned long long* __restrict__ mdiag,
    float* __restrict__ out)   // [B*POST*4] boxes then [B*POST] scores
{
    #pragma clang fp contract(off)
    const int b = blockIdx.x;
    const int tid = threadIdx.x;
    __shared__ __align__(16) unsigned long long Ml[TRI_WORDS];
    __shared__ int sidx[POST];
    __shared__ int s_kc;

    // wave0: diagonal words, lane l -> row W*64+l's word W (coalesced per W)
    unsigned int dlo[NW], dhi[NW];
    if (tid < 64) {
        const int lane = tid;
        const unsigned long long* Db = mdiag + ((size_t)b << 10);
        #pragma unroll
        for (int W = 0; W < NW; ++W) {
            const int base = W << 6;
            const int nvalid = (PRE - base < 64) ? (PRE - base) : 64;
            unsigned long long dv = Db[base + lane];
            if (lane >= nvalid) dv = 0ull;
            dlo[W] = (unsigned int)dv;
            dhi[W] = (unsigned int)(dv >> 32);
        }
    }

    // all threads: linear coalesced copy of the tri block (3900 float4)
    {
        const float4* src = (const float4*)(mtri + (size_t)b * TRI_WORDS);
        float4* dst = (float4*)Ml;
        for (int idx = tid; idx < TRI_WORDS / 2; idx += 512) dst[idx] = src[idx];
    }
    __syncthreads();

    if (tid < 64) {
        const int lane = tid;
        const int wword = lane & 15;
        const int wgrp  = lane >> 4;
        unsigned long long rm = 0ull;   // distributed removed word (l&15), group partial
        int kc = 0;
        bool done = false;
        #pragma unroll
        for (int W = 0; W < NW; ++W) {
            const int base = W << 6;
            // merge the 4 group partials of removed word W -> uniform
            unsigned int rlo = (unsigned int)__builtin_amdgcn_readlane((int)(unsigned int)rm, W)
                             | (unsigned int)__builtin_amdgcn_readlane((int)(unsigned int)rm, W + 16)
                             | (unsigned int)__builtin_amdgcn_readlane((int)(unsigned int)rm, W + 32)
                             | (unsigned int)__builtin_amdgcn_readlane((int)(unsigned int)rm, W + 48);
            unsigned int rhi = (unsigned int)__builtin_amdgcn_readlane((int)(unsigned int)(rm >> 32), W)
                             | (unsigned int)__builtin_amdgcn_readlane((int)(unsigned int)(rm >> 32), W + 16)
                             | (unsigned int)__builtin_amdgcn_readlane((int)(unsigned int)(rm >> 32), W + 32)
                             | (unsigned int)__builtin_amdgcn_readlane((int)(unsigned int)(rm >> 32), W + 48);
            unsigned long long rmW = ((unsigned long long)rhi << 32) | (unsigned long long)rlo;
            unsigned long long valid = (PRE - base >= 64) ? ~0ull : ((1ull << (PRE - base)) - 1ull);
            unsigned long long alive = ~rmW & valid;
            unsigned long long keptw = 0ull;
            while (alive) {
                int i = __builtin_amdgcn_readfirstlane(__ffsll(alive) - 1);
                keptw |= (1ull << i);
                if (lane == 0) sidx[kc] = base + i;
                ++kc;
                if (kc == POST) { done = true; break; }
                unsigned int dl = (unsigned int)__builtin_amdgcn_readlane((int)dlo[W], i);
                unsigned int dh = (unsigned int)__builtin_amdgcn_readlane((int)dhi[W], i);
                unsigned long long d = ((unsigned long long)dh << 32) | (unsigned long long)dl;
                alive &= ~(d | (1ull << i));
            }
            if (done) break;
            // flush kept rows' masks into distributed rm; 8 rows per round (A+B)
            const int cgW = 15 * W - (W * (W - 1)) / 2;   // compile-time (W unrolled)
            unsigned long long kw = keptw;
            while (kw) {
                unsigned long long tA = kw;
                if (wgrp > 0) tA &= tA - 1ull;
                if (wgrp > 1) tA &= tA - 1ull;
                if (wgrp > 2) tA &= tA - 1ull;
                const bool vA = (tA != 0ull);
                const int iA = vA ? (__ffsll(tA) - 1) : 0;
                unsigned long long kw2 = kw;
                kw2 &= kw2 - 1ull; kw2 &= kw2 - 1ull; kw2 &= kw2 - 1ull; kw2 &= kw2 - 1ull;
                unsigned long long tB = kw2;
                if (wgrp > 0) tB &= tB - 1ull;
                if (wgrp > 1) tB &= tB - 1ull;
                if (wgrp > 2) tB &= tB - 1ull;
                const bool vB = (tB != 0ull);
                const int iB = vB ? (__ffsll(tB) - 1) : 0;
                kw = kw2;
                kw &= kw - 1ull; kw &= kw - 1ull; kw &= kw - 1ull; kw &= kw - 1ull;
                // lane's word for row i{A,B}: wword>W -> LDS tri; ==W -> diag regs; <W -> 0
                unsigned long long lA = 0ull, lB = 0ull;
                if (wword > W) {
                    const int col = cgW + (wword - W - 1);
                    lA = Ml[col * TRIP + iA];
                    lB = Ml[col * TRIP + iB];
                }
                unsigned long long gA =
                    ((unsigned long long)(unsigned int)__builtin_amdgcn_readlane((int)dhi[W], iA) << 32)
                  |  (unsigned long long)(unsigned int)__builtin_amdgcn_readlane((int)dlo[W], iA);
                unsigned long long gB =
                    ((unsigned long long)(unsigned int)__builtin_amdgcn_readlane((int)dhi[W], iB) << 32)
                  |  (unsigned long long)(unsigned int)__builtin_amdgcn_readlane((int)dlo[W], iB);
                unsigned long long mA = (wword > W) ? lA : ((wword == W) ? gA : 0ull);
                unsigned long long mB = (wword > W) ? lB : ((wword == W) ? gB : 0ull);
                if (!vA) mA = 0ull;
                if (!vB) mB = 0ull;
                rm |= mA | mB;
            }
        }
        if (tid == 0) s_kc = kc;
    }
    __syncthreads();

    const int kc = s_kc;
    const float4* bb = tboxes + (size_t)b * PRE;
    const float* ss = tscores + (size_t)b * PRE;
    float4* oB = (float4*)out + (size_t)b * POST;
    float* oS = out + (size_t)BATCH * POST * 4 + (size_t)b * POST;
    for (int t2 = tid; t2 < POST; t2 += 512) {
        float4 v = make_float4(0.f, 0.f, 0.f, 0.f);
        float sc = 0.f;
        if (t2 < kc) {
            int r = sidx[t2];
            float4 bx = bb[r];
            v.x = fminf(fmaxf(bx.x, 0.f), 1.f);
            v.y = fminf(fmaxf(bx.y, 0.f), 1.f);
            v.z = fminf(fmaxf(bx.z, 0.f), 1.f);
            v.w = fminf(fmaxf(bx.w, 0.f), 1.f);
            sc = ss[r];
        }
        oB[t2] = v;
        oS[t2] = sc;
    }
}

extern "C" void kernel_launch(void* const* d_in, const int* in_sizes, int n_in,
                              void* d_out, int out_size, void* d_ws, size_t ws_size,
                              hipStream_t stream) {
    const float* deltas  = (const float*)d_in[0];   // [64,8649,4] f32
    const float* probs   = (const float*)d_in[1];   // [64,8649]   f32
    const float* anchors = (const float*)d_in[3];   // [8649,4]    f32
    float* out = (float*)d_out;

    char* ws = (char*)d_ws;
    float4* tboxes = (float4*)ws;                                    // 1,024,000 B
    float* tscores = (float*)(ws + 1024000);                         //   256,000 B
    float* tareas  = (float*)(ws + 1280000);                         //   256,000 B
    unsigned long long* mdiag = (unsigned long long*)(ws + 1536000); //   524,288 B
    unsigned long long* mtri  = (unsigned long long*)(ws + 2060288); // 3,993,600 B

    k_topk_decode<<<dim3(BATCH), dim3(1024), 0, stream>>>(deltas, probs, anchors,
                                                          tboxes, tscores, tareas);
    k_masks<<<dim3(34, BATCH), dim3(256), 0, stream>>>(tboxes, tareas, mtri, mdiag);
    k_nms_out<<<dim3(BATCH), dim3(512), 0, stream>>>(tboxes, tscores, mtri, mdiag, out);
}